// Round 7
// baseline (1398.910 us; speedup 1.0000x reference)
//
#include <hip/hip_runtime.h>
#include <math.h>

// Problem constants
#define BB   4
#define SS   2048
#define DD   2048
#define HH   16
#define DHH  128
#define NROWS (BB*SS)   // 8192

typedef _Float16 h16;
typedef __attribute__((ext_vector_type(8))) _Float16 half8;
typedef __attribute__((ext_vector_type(4))) _Float16 half4;
typedef __attribute__((ext_vector_type(4))) float f32x4;

// ---------------------------------------------------------------- helpers
__device__ __forceinline__ void gload_lds16(const void* g, void* l) {
    __builtin_amdgcn_global_load_lds(
        (const __attribute__((address_space(1))) void*)g,
        (__attribute__((address_space(3))) void*)l,
        16, 0, 0);
}

// ---------------------------------------------------------------- casts
__global__ void cast_f32_to_f16(const float* __restrict__ src,
                                h16* __restrict__ dst, int n8) {
    int i = blockIdx.x * 256 + threadIdx.x;
    if (i >= n8) return;
    f32x4 a = ((const f32x4*)src)[2*i];
    f32x4 b = ((const f32x4*)src)[2*i + 1];
    half8 o;
    o[0]=(h16)a[0]; o[1]=(h16)a[1]; o[2]=(h16)a[2]; o[3]=(h16)a[3];
    o[4]=(h16)b[0]; o[5]=(h16)b[1]; o[6]=(h16)b[2]; o[7]=(h16)b[3];
    ((half8*)dst)[i] = o;
}

// three small LoRA-up tensors in one dispatch (16 blocks each)
__global__ void cast3_f32_to_f16(const float* __restrict__ s0, h16* __restrict__ d0,
                                 const float* __restrict__ s1, h16* __restrict__ d1,
                                 const float* __restrict__ s2, h16* __restrict__ d2) {
    const int which = blockIdx.x >> 4;
    const int i = (blockIdx.x & 15) * 256 + threadIdx.x;   // < 4096 each
    const float* src = (which == 0) ? s0 : (which == 1) ? s1 : s2;
    h16*       dst = (which == 0) ? d0 : (which == 1) ? d1 : d2;
    f32x4 a = ((const f32x4*)src)[2*i];
    f32x4 b = ((const f32x4*)src)[2*i + 1];
    half8 o;
    o[0]=(h16)a[0]; o[1]=(h16)a[1]; o[2]=(h16)a[2]; o[3]=(h16)a[3];
    o[4]=(h16)b[0]; o[5]=(h16)b[1]; o[6]=(h16)b[2]; o[7]=(h16)b[3];
    ((half8*)dst)[i] = o;
}

// ---------------------------------------------------------------- LoRA down, single-pass:
// t[p][row][r] = 2 * x[row,:] . ld_p[r,:]  for p in {q,k,v} — reads the fp16 x
// row ONCE (3 accumulators), vs 3 fp32 passes (201 MB -> 34 MB traffic).
__global__ void lora_down_kernel(const h16* __restrict__ xb,
                                 const float* __restrict__ lqd,
                                 const float* __restrict__ lkd,
                                 const float* __restrict__ lvd,
                                 h16* __restrict__ tb) {
    const int row = blockIdx.x * 16 + (threadIdx.x >> 4);
    const int r   = threadIdx.x & 15;
    const h16*   xr = xb  + (size_t)row * DD;
    const float* qr = lqd + (size_t)r   * DD;
    const float* kr = lkd + (size_t)r   * DD;
    const float* vr = lvd + (size_t)r   * DD;
    float aq = 0.f, ak = 0.f, av = 0.f;
    for (int k = 0; k < DD; k += 8) {
        half8 xv = *(const half8*)(xr + k);
        f32x4 q0 = *(const f32x4*)(qr + k), q1 = *(const f32x4*)(qr + k + 4);
        f32x4 k0 = *(const f32x4*)(kr + k), k1 = *(const f32x4*)(kr + k + 4);
        f32x4 v0 = *(const f32x4*)(vr + k), v1 = *(const f32x4*)(vr + k + 4);
        #pragma unroll
        for (int j = 0; j < 4; ++j) {
            const float a = (float)xv[j], b = (float)xv[4 + j];
            aq += a * q0[j] + b * q1[j];
            ak += a * k0[j] + b * k1[j];
            av += a * v0[j] + b * v1[j];
        }
    }
    tb[((size_t)0 * NROWS + row) * 16 + r] = (h16)(aq * 2.0f);
    tb[((size_t)1 * NROWS + row) * 16 + r] = (h16)(ak * 2.0f);
    tb[((size_t)2 * NROWS + row) * 16 + r] = (h16)(av * 2.0f);
}

// ---------------------------------------------------------------- GEMM  C = A @ W^T (+ LoRA)
// m97 tile + T1 XCD swizzle + minimum 2-phase LDS double-buffer (T3 recipe):
// prologue stages buf0; each K-step issues next tile's global_load_lds into
// buf^1 BEFORE ds_read+MFMA of buf, then ONE __syncthreads (vmcnt drain +
// barrier) per step. Re-stage of a buffer is safe: all ds_reads of it were
// consumed (lgkmcnt) before the previous barrier. LDS 64 KB -> still 2
// blocks/CU (= launch_bounds cap; m132 regression regime not entered).
// MODE 0: +LoRA, +fused RoPE, write h16 to [B,H,S,DH] (Q/K).
// MODE 1: +LoRA, write h16 to [B,H,DH,S] (V^T).
// MODE 2: no LoRA, write fp32 natural [NROWS,D] (final output).
template<int MODE>
__global__ __launch_bounds__(256, 2)
void gemm_bt(const h16* __restrict__ A, const h16* __restrict__ W,
             const h16* __restrict__ tb, const h16* __restrict__ ub,
             const float* __restrict__ fc, const float* __restrict__ fs,
             void* __restrict__ outp) {
    __shared__ char smem[65536];           // [buf][A 16K | B 16K], buf = 0/1
    const int tid = threadIdx.x;
    const int lane = tid & 63;
    const int w  = tid >> 6;
    const int wr = w >> 1, wc = w & 1;
    const int ln = lane & 15, lg = lane >> 4;

    // T1: bijective XCD swizzle (nwg = 16*64 = 1024, 1024 % 8 == 0).
    const int lid = blockIdx.y * 16 + blockIdx.x;
    const int swz = (lid & 7) * 128 + (lid >> 3);
    const int brow = (swz >> 4) * 128;
    const int bcol = (swz & 15) * 128;

    f32x4 acc[4][4] = {};

    const char* Ag = (const char*)(A + (size_t)brow * DD);
    const char* Wg = (const char*)(W + (size_t)bcol * DD);
    const size_t ldb = DD * 2;

    // stage one 128x64 A-tile + B-tile into buffer `buf` (linear LDS dest +
    // inverse-swizzled global source, rule #21)
    auto STAGE = [&](int buf, int kt) {
        const int ktb = kt * 128;
        const int base = buf << 15;
        #pragma unroll
        for (int i = 0; i < 4; ++i) {
            const int L   = i * 4096 + tid * 16;
            const int row = L >> 7;
            const int off = L & 127;
            const int soff = ktb + (off ^ ((row & 7) << 4));
            gload_lds16(Ag + (size_t)row * ldb + soff, smem + base + L);
            gload_lds16(Wg + (size_t)row * ldb + soff, smem + base + 16384 + L);
        }
    };

    constexpr int NT = DD / 64;            // 32 K-steps
    STAGE(0, 0);
    __syncthreads();                       // vmcnt(0) drain + barrier
    int cur = 0;
    for (int kt = 0; kt < NT; ++kt) {
        if (kt + 1 < NT) STAGE(cur ^ 1, kt + 1);   // overlap with compute below
        const char* sb = smem + (cur << 15);
        #pragma unroll
        for (int ks = 0; ks < 2; ++ks) {
            half8 af[4], bfr[4];
            const int cb = (ks * 32 + lg * 8) * 2;
            #pragma unroll
            for (int m = 0; m < 4; ++m) {
                const int r = wr * 64 + m * 16 + ln;
                af[m] = *(const half8*)(sb + r * 128 + (cb ^ ((r & 7) << 4)));
            }
            #pragma unroll
            for (int n = 0; n < 4; ++n) {
                const int r = wc * 64 + n * 16 + ln;
                bfr[n] = *(const half8*)(sb + 16384 + r * 128 + (cb ^ ((r & 7) << 4)));
            }
            #pragma unroll
            for (int m = 0; m < 4; ++m)
                #pragma unroll
                for (int n = 0; n < 4; ++n)
                    acc[m][n] = __builtin_amdgcn_mfma_f32_16x16x32_f16(
                        af[m], bfr[n], acc[m][n], 0, 0, 0);
        }
        __syncthreads();                   // next-tile stage landed; readers done
        cur ^= 1;
    }

    if (MODE != 2) {
        // ---- LoRA up via one K=32 MFMA round (upper 16 of K zero-padded)
        h16* tl = (h16*)smem;              // [128][32]
        h16* ul = (h16*)(smem + 8192);     // [128][32]
        {
            half8 z = {};
            if (tid < 128) {
                const half8* s = (const half8*)(tb + (size_t)(brow + tid) * 16);
                half8* d = (half8*)(tl + tid * 32);
                d[0] = s[0]; d[1] = s[1]; d[2] = z; d[3] = z;
            } else {
                const int c = tid - 128;
                const half8* s = (const half8*)(ub + (size_t)(bcol + c) * 16);
                half8* d = (half8*)(ul + c * 32);
                d[0] = s[0]; d[1] = s[1]; d[2] = z; d[3] = z;
            }
        }
        __syncthreads();
        half8 ta[4], ua[4];
        #pragma unroll
        for (int m = 0; m < 4; ++m)
            ta[m] = *(const half8*)(tl + (wr * 64 + m * 16 + ln) * 32 + lg * 8);
        #pragma unroll
        for (int n = 0; n < 4; ++n)
            ua[n] = *(const half8*)(ul + (wc * 64 + n * 16 + ln) * 32 + lg * 8);
        #pragma unroll
        for (int m = 0; m < 4; ++m)
            #pragma unroll
            for (int n = 0; n < 4; ++n)
                acc[m][n] = __builtin_amdgcn_mfma_f32_16x16x32_f16(
                    ta[m], ua[n], acc[m][n], 0, 0, 0);
    }

    // ---- write per mode (C layout: col = ln, rows = lg*4+i  [m89-verified])
    if (MODE == 0) {
        // Fused RoPE: pair (dh, dh^1) lives in (lane, lane^1) at the same grow
        // (n*16 even => dh parity == ln parity; lg identical across the pair).
        h16* O = (h16*)outp;
        const bool odd = ln & 1;
        #pragma unroll
        for (int m = 0; m < 4; ++m)
            #pragma unroll
            for (int n = 0; n < 4; ++n) {
                const int gcol = bcol + wc * 64 + n * 16 + ln;
                const int hh = gcol >> 7, dh = gcol & 127;
                const int j  = dh >> 1;                    // rope pair index
                #pragma unroll
                for (int i = 0; i < 4; ++i) {
                    const int grow = brow + wr * 64 + m * 16 + lg * 4 + i;
                    const int b = grow >> 11, s = grow & (SS - 1);
                    const float own = acc[m][n][i];
                    const float prt = __shfl_xor(own, 1);
                    const float cs = fc[s * 64 + j];
                    const float sn = fs[s * 64 + j];
                    // even dh: a=own, b=prt -> a*c - b*s ; odd dh: a=prt, b=own -> a*s + b*c
                    const float outv = odd ? (prt * sn + own * cs)
                                           : (own * cs - prt * sn);
                    O[(((size_t)(b * HH + hh) * SS + s) << 7) + dh] = (h16)outv;
                }
            }
    } else if (MODE == 1) {
        h16* O = (h16*)outp;
        #pragma unroll
        for (int m = 0; m < 4; ++m)
            #pragma unroll
            for (int n = 0; n < 4; ++n) {
                const int gcol = bcol + wc * 64 + n * 16 + ln;
                const int hh = gcol >> 7, dh = gcol & 127;
                const int grow0 = brow + wr * 64 + m * 16 + lg * 4;
                const int b = grow0 >> 11, s0 = grow0 & (SS - 1);
                half4 pk = { (h16)acc[m][n][0], (h16)acc[m][n][1],
                             (h16)acc[m][n][2], (h16)acc[m][n][3] };
                *(half4*)(O + ((size_t)(b * HH + hh) * DHH + dh) * SS + s0) = pk;
            }
    } else {
        float* O = (float*)outp;
        #pragma unroll
        for (int m = 0; m < 4; ++m)
            #pragma unroll
            for (int n = 0; n < 4; ++n) {
                const int gcol = bcol + wc * 64 + n * 16 + ln;
                #pragma unroll
                for (int i = 0; i < 4; ++i) {
                    const int grow = brow + wr * 64 + m * 16 + lg * 4 + i;
                    O[(size_t)grow * DD + gcol] = acc[m][n][i];
                }
            }
    }
}

// ---------------------------------------------------------------- causal flash attention
// Q,K: [B,H,S,DH] fp16 (roped).  Vt: [B,H,DH,S] fp16.  Out: [B*S, H*DH] fp16.
// T1: XCD swizzle so each XCD owns a contiguous bh range (K/V L2-resident).
// T5: setprio around MFMA bursts.  T13: defer-max (THR=8, m214v23 pattern).
__global__ __launch_bounds__(256, 1)
void attn_kernel(const h16* __restrict__ Q, const h16* __restrict__ K,
                 const h16* __restrict__ Vt, h16* __restrict__ Aout) {
    __shared__ __align__(16) h16 Plds[4][32 * 80];     // per-wave, stride 80
    const int tid = threadIdx.x;
    const int lane = tid & 63;
    const int w  = tid >> 6;
    const int ln = lane & 15, lg = lane >> 4;

    // T1: bijective XCD swizzle (nwg = 16*64 = 1024). XCD k -> bh in [8k, 8k+8),
    // all 16 q-blocks of a bh consecutive -> that head's 1 MB K/V stays in its L2.
    const int lid = blockIdx.y * 16 + blockIdx.x;
    const int swz = (lid & 7) * 128 + (lid >> 3);
    const int bh  = swz >> 4;
    const int q0  = (swz & 15) * 128 + w * 32;         // wave's q base

    const h16* Qh = Q  + ((size_t)bh << 18);           // *S*DH
    const h16* Kh = K  + ((size_t)bh << 18);
    const h16* Vh = Vt + ((size_t)bh << 18);

    half8 qf[2][4];
    #pragma unroll
    for (int m = 0; m < 2; ++m)
        #pragma unroll
        for (int ks = 0; ks < 4; ++ks)
            qf[m][ks] = *(const half8*)(Qh + (((size_t)(q0 + m*16 + ln)) << 7)
                                           + ks * 32 + lg * 8);

    f32x4 oacc[2][8] = {};
    float mr[2][4], lr[2][4];
    #pragma unroll
    for (int m = 0; m < 2; ++m)
        #pragma unroll
        for (int i = 0; i < 4; ++i) { mr[m][i] = -INFINITY; lr[m][i] = 0.f; }

    const float scale = 0.08838834764831845f;          // 1/sqrt(128)
    const int ktend = (q0 + 31) >> 6;                  // last K-tile (inclusive)
    for (int kt = 0; kt <= ktend; ++kt) {
        const int kb = kt * 64;
        f32x4 sa[2][4] = {};
        #pragma unroll
        for (int ks = 0; ks < 4; ++ks) {
            half8 kf[4];
            #pragma unroll
            for (int n = 0; n < 4; ++n)
                kf[n] = *(const half8*)(Kh + (((size_t)(kb + n*16 + ln)) << 7)
                                           + ks * 32 + lg * 8);
            __builtin_amdgcn_s_setprio(1);             // T5
            #pragma unroll
            for (int m = 0; m < 2; ++m)
                #pragma unroll
                for (int n = 0; n < 4; ++n)
                    sa[m][n] = __builtin_amdgcn_mfma_f32_16x16x32_f16(
                        qf[m][ks], kf[n], sa[m][n], 0, 0, 0);
            __builtin_amdgcn_s_setprio(0);
        }
        // scale + causal mask
        #pragma unroll
        for (int m = 0; m < 2; ++m)
            #pragma unroll
            for (int n = 0; n < 4; ++n) {
                const int kpos = kb + n * 16 + ln;
                #pragma unroll
                for (int i = 0; i < 4; ++i) {
                    const int qrow = q0 + m * 16 + lg * 4 + i;
                    const float v2 = sa[m][n][i] * scale;
                    sa[m][n][i] = (kpos <= qrow) ? v2 : -1e9f;
                }
            }
        // ---- row maxes (uniform across the 16 ln lanes of each lg group)
        float mx[2][4];
        float gmax = -INFINITY;                         // max growth over this lane's rows
        #pragma unroll
        for (int m = 0; m < 2; ++m)
            #pragma unroll
            for (int i = 0; i < 4; ++i) {
                float v = fmaxf(fmaxf(sa[m][0][i], sa[m][1][i]),
                                fmaxf(sa[m][2][i], sa[m][3][i]));
                v = fmaxf(v, __shfl_xor(v, 1));
                v = fmaxf(v, __shfl_xor(v, 2));
                v = fmaxf(v, __shfl_xor(v, 4));
                v = fmaxf(v, __shfl_xor(v, 8));
                mx[m][i] = v;
                gmax = fmaxf(gmax, v - mr[m][i]);
            }
        // T13 defer-max: if no row grew past THR=8, keep old max — skip the
        // oacc rescale + lr re-exponentiation. P bounded by e^8 (~2981, fp16-safe);
        // final oacc/lr ratio unaffected. First tile: mr=-inf -> +inf growth -> full path.
        if (__any(gmax > 8.0f)) {
            #pragma unroll
            for (int m = 0; m < 2; ++m)
                #pragma unroll
                for (int i = 0; i < 4; ++i) {
                    const float mn = fmaxf(mr[m][i], mx[m][i]);
                    const float f  = __expf(mr[m][i] - mn);
                    mr[m][i] = mn;
                    lr[m][i] *= f;
                    #pragma unroll
                    for (int d = 0; d < 8; ++d) oacc[m][d][i] *= f;
                    float psum = 0.f;
                    #pragma unroll
                    for (int n = 0; n < 4; ++n) {
                        const float p = __expf(sa[m][n][i] - mn);
                        psum += p;
                        Plds[w][(m*16 + lg*4 + i) * 80 + n*16 + ln] = (h16)p;
                    }
                    lr[m][i] += psum;
                }
        } else {
            #pragma unroll
            for (int m = 0; m < 2; ++m)
                #pragma unroll
                for (int i = 0; i < 4; ++i) {
                    float psum = 0.f;
                    #pragma unroll
                    for (int n = 0; n < 4; ++n) {
                        const float p = __expf(sa[m][n][i] - mr[m][i]);
                        psum += p;
                        Plds[w][(m*16 + lg*4 + i) * 80 + n*16 + ln] = (h16)p;
                    }
                    lr[m][i] += psum;
                }
        }
        asm volatile("s_waitcnt lgkmcnt(0)" ::: "memory");  // P writes landed (per-wave, in-order DS)
        // PV
        #pragma unroll
        for (int k2 = 0; k2 < 2; ++k2) {
            half8 pf[2];
            #pragma unroll
            for (int m = 0; m < 2; ++m)
                pf[m] = *(const half8*)(&Plds[w][(m*16 + ln) * 80 + k2*32 + lg*8]);
            #pragma unroll
            for (int n = 0; n < 8; ++n) {
                half8 vf = *(const half8*)(Vh + (((size_t)(n*16 + ln)) << 11)
                                              + kb + k2 * 32 + lg * 8);
                __builtin_amdgcn_s_setprio(1);         // T5
                #pragma unroll
                for (int m = 0; m < 2; ++m)
                    oacc[m][n] = __builtin_amdgcn_mfma_f32_16x16x32_f16(
                        pf[m], vf, oacc[m][n], 0, 0, 0);
                __builtin_amdgcn_s_setprio(0);
            }
        }
    }
    // finalize
    #pragma unroll
    for (int m = 0; m < 2; ++m)
        #pragma unroll
        for (int i = 0; i < 4; ++i) {
            float l = lr[m][i];
            l += __shfl_xor(l, 1); l += __shfl_xor(l, 2);
            l += __shfl_xor(l, 4); l += __shfl_xor(l, 8);
            lr[m][i] = 1.f / l;
        }
    const int b = bh >> 4, hh = bh & 15;
    #pragma unroll
    for (int m = 0; m < 2; ++m)
        #pragma unroll
        for (int n = 0; n < 8; ++n) {
            const int col = hh * 128 + n * 16 + ln;
            #pragma unroll
            for (int i = 0; i < 4; ++i) {
                const int qrow = q0 + m * 16 + lg * 4 + i;
                Aout[(((size_t)(b * SS + qrow)) << 11) + col] =
                    (h16)(oacc[m][n][i] * lr[m][i]);
            }
        }
}

// ---------------------------------------------------------------- launch
extern "C" void kernel_launch(void* const* d_in, const int* in_sizes, int n_in,
                              void* d_out, int out_size, void* d_ws, size_t ws_size,
                              hipStream_t stream) {
    const float* x   = (const float*)d_in[0];
    const float* wq  = (const float*)d_in[1];
    const float* wk  = (const float*)d_in[2];
    const float* wv  = (const float*)d_in[3];
    const float* wo  = (const float*)d_in[4];
    const float* lqd = (const float*)d_in[5];
    const float* lqu = (const float*)d_in[6];
    const float* lkd = (const float*)d_in[7];
    const float* lku = (const float*)d_in[8];
    const float* lvd = (const float*)d_in[9];
    const float* lvu = (const float*)d_in[10];
    const float* fc  = (const float*)d_in[11];
    const float* fs  = (const float*)d_in[12];
    // d_in[13] = mask, unused (causal mask applied analytically)

    // Workspace layout (~137 MB). Single reused fp16 weight slot: the stream
    // serializes all dispatches anyway, so cast->gemm->cast->gemm loses nothing.
    char* ws = (char*)d_ws;
    h16* xb    = (h16*)(ws);                        // [8192,2048] h16, 33554432 B
    h16* wslot = (h16*)(ws + 33554432);             // 8388608 B, reused 4x
    h16* lqub  = (h16*)(ws + 41943040);             // 65536 B each
    h16* lkub  = (h16*)(ws + 42008576);
    h16* lvub  = (h16*)(ws + 42074112);
    h16* tb    = (h16*)(ws + 42139648);             // [3][8192][16] = 786432 B
    h16* Qb    = (h16*)(ws + 42926080);             // [B,H,S,DH]  33554432 B
    h16* Kb    = (h16*)(ws + 76480512);             // [B,H,S,DH]
    h16* Vtb   = (h16*)(ws + 110034944);            // [B,H,DH,S]; end 143589376
    h16* aout  = xb;                                // xb dead after V GEMM

    cast_f32_to_f16<<<8192, 256, 0, stream>>>(x,  xb,  NROWS * DD / 8);
    cast3_f32_to_f16<<<48, 256, 0, stream>>>(lqu, lqub, lku, lkub, lvu, lvub);

    // single pass over xb, 3 accumulators
    lora_down_kernel<<<512, 256, 0, stream>>>(xb, lqd, lkd, lvd, tb);

    cast_f32_to_f16<<<2048, 256, 0, stream>>>(wq, wslot, DD * DD / 8);
    gemm_bt<0><<<dim3(16, 64), 256, 0, stream>>>(xb, wslot, tb,              lqub, fc, fs, Qb);
    cast_f32_to_f16<<<2048, 256, 0, stream>>>(wk, wslot, DD * DD / 8);
    gemm_bt<0><<<dim3(16, 64), 256, 0, stream>>>(xb, wslot, tb + NROWS*16,   lkub, fc, fs, Kb);
    cast_f32_to_f16<<<2048, 256, 0, stream>>>(wv, wslot, DD * DD / 8);
    gemm_bt<1><<<dim3(16, 64), 256, 0, stream>>>(xb, wslot, tb + 2*NROWS*16, lvub, nullptr, nullptr, Vtb);

    attn_kernel<<<dim3(16, 64), 256, 0, stream>>>(Qb, Kb, Vtb, aout);

    cast_f32_to_f16<<<2048, 256, 0, stream>>>(wo, wslot, DD * DD / 8);
    gemm_bt<2><<<dim3(16, 64), 256, 0, stream>>>(aout, wslot, nullptr, nullptr, nullptr, nullptr, d_out);
}